// Round 6
// baseline (2032.061 us; speedup 1.0000x reference)
//
#include <hip/hip_runtime.h>
#include <hip/hip_bf16.h>
#include <stdint.h>

typedef __bf16 bf16_t;
typedef __bf16 bf16x8 __attribute__((ext_vector_type(8)));
typedef __bf16 bf16x4 __attribute__((ext_vector_type(4)));
typedef float  floatx4 __attribute__((ext_vector_type(4)));

#define T_STEPS 128
#define BATCH   64
#define EDIM    1024
#define HDIM    1024
#define VOCAB   10000
#define MROWS   (T_STEPS * BATCH)   // 8192
#define RNN_BLOCKS 64               // fused layer-0 + layer-1 blocks, 16 cols each
#define BH      (BATCH * HDIM)
#define FSTRIDE 16                  // flags padded to one 64B line each (dword stride 16)

__device__ __forceinline__ floatx4 mfma16(bf16x8 a, bf16x8 b, floatx4 c) {
    return __builtin_amdgcn_mfma_f32_16x16x32_bf16(a, b, c, 0, 0, 0);
}

// async global->LDS, 16B per lane. LDS dest must be wave-uniform base + lane*16.
__device__ __forceinline__ void gl_lds16(const bf16_t* g, bf16_t* l) {
    __builtin_amdgcn_global_load_lds(
        (const __attribute__((address_space(1))) void*)g,
        (__attribute__((address_space(3))) void*)l, 16, 0, 0);
}

// Coherence-point store: bypasses L1/L2 (sc0 sc1), lands at L3 so other XCDs'
// first-touch plain loads see it WITHOUT any buffer_wbl2/buffer_inv.
__device__ __forceinline__ void store_bf16_bypass(bf16_t* p, float v) {
    union { bf16_t b; unsigned short u; } cv;
    cv.b = (bf16_t)v;
    unsigned int d = cv.u;
    asm volatile("global_store_short %0, %1, off sc0 sc1"
                 :: "v"(p), "v"(d) : "memory");
}

// ---------------- setup kernels ----------------

__global__ void f2b_kernel(const float* __restrict__ s, bf16_t* __restrict__ d, int n) {
    int i = (blockIdx.x * blockDim.x + threadIdx.x) * 4;
    if (i < n) {
        float4 v = *(const float4*)(s + i);
        bf16x4 o;
        o.x = (bf16_t)v.x; o.y = (bf16_t)v.y; o.z = (bf16_t)v.z; o.w = (bf16_t)v.w;
        *(bf16x4*)(d + i) = o;
    }
}

__global__ void gather_kernel(const float* __restrict__ emb, const int* __restrict__ tok,
                              bf16_t* __restrict__ X) {
    int row = blockIdx.x;
    int t = tok[row];
    int e = threadIdx.x * 4;
    float4 v = *(const float4*)(emb + (size_t)t * EDIM + e);
    bf16x4 o;
    o.x = (bf16_t)v.x; o.y = (bf16_t)v.y; o.z = (bf16_t)v.z; o.w = (bf16_t)v.w;
    *(bf16x4*)(X + (size_t)row * EDIM + e) = o;
}

__global__ void init_state_kernel(const float* __restrict__ hidden,
                                  bf16_t* __restrict__ h0all, bf16_t* __restrict__ h1all,
                                  int* __restrict__ flags) {
    int i = blockIdx.x * blockDim.x + threadIdx.x;   // 65536 threads
    h0all[i] = (bf16_t)hidden[i];                    // h0[-1] -> h0all slot 0
    h1all[i] = (bf16_t)hidden[BATCH * HDIM + i];     // h1[-1] -> h1all slot 0
    if (i < 128 * FSTRIDE) flags[i] = 0;
}

// ---------------- big GEMM: C[M,N] = A[M,K] @ W[N,K]^T + bias ----------------
// 128x128 tile, BK=32, 4 waves (2x2), 4x4 MFMA 16x16x32 per wave.
// Staging via global_load_lds width=16 (m97 pattern).

template <int OUT_BF16>
__global__ __launch_bounds__(256) void gemm_kernel(
    const bf16_t* __restrict__ A, const bf16_t* __restrict__ W,
    const float* __restrict__ bias, void* __restrict__ out,
    int M, int N, int K)
{
    const int tid  = threadIdx.x;
    const int lane = tid & 63;
    const int wave = tid >> 6;
    const int wm   = wave & 1;
    const int wn   = wave >> 1;
    const int quad = lane >> 4;
    const int l16  = lane & 15;
    const int mTile = blockIdx.y * 128;
    const int nTile = blockIdx.x * 128;

    __shared__ __align__(16) bf16_t sA[128 * 32];
    __shared__ __align__(16) bf16_t sW[128 * 32];

    const floatx4 fzero = {0.f, 0.f, 0.f, 0.f};
    floatx4 acc[4][4];
    #pragma unroll
    for (int i = 0; i < 4; ++i)
        #pragma unroll
        for (int j = 0; j < 4; ++j) acc[i][j] = fzero;

    for (int kk = 0; kk < K; kk += 32) {
        __syncthreads();
        #pragma unroll
        for (int j = 0; j < 2; ++j) {
            int c   = tid + j * 256;     // chunk 0..511, 16B each; LDS dst = c*16 bytes
            int row = c >> 2;
            int sub = c & 3;
            gl_lds16(A + (size_t)(mTile + row) * K + kk + sub * 8, sA + c * 8);
            int wrow = nTile + row;
            if (wrow >= N) wrow = N - 1;  // clamp for V=10000 edge tile
            gl_lds16(W + (size_t)wrow * K + kk + sub * 8, sW + c * 8);
        }
        __syncthreads();                 // compiler drains vmcnt before s_barrier
        bf16x8 af[4], wf[4];
        #pragma unroll
        for (int mi = 0; mi < 4; ++mi)
            af[mi] = *(const bf16x8*)(sA + (wm * 64 + mi * 16 + l16) * 32 + quad * 8);
        #pragma unroll
        for (int ni = 0; ni < 4; ++ni)
            wf[ni] = *(const bf16x8*)(sW + (wn * 64 + ni * 16 + l16) * 32 + quad * 8);
        #pragma unroll
        for (int mi = 0; mi < 4; ++mi)
            #pragma unroll
            for (int ni = 0; ni < 4; ++ni)
                acc[mi][ni] = mfma16(af[mi], wf[ni], acc[mi][ni]);
    }

    #pragma unroll
    for (int ni = 0; ni < 4; ++ni) {
        int col = nTile + wn * 64 + ni * 16 + l16;
        if (col < N) {
            float bv = bias[col];
            #pragma unroll
            for (int mi = 0; mi < 4; ++mi) {
                #pragma unroll
                for (int r = 0; r < 4; ++r) {
                    int row = mTile + wm * 64 + mi * 16 + quad * 4 + r;
                    float v = acc[mi][ni][r] + bv;
                    if (OUT_BF16) ((bf16_t*)out)[(size_t)row * N + col] = (bf16_t)v;
                    else          ((float*)out)[(size_t)row * N + col] = v;
                }
            }
        }
    }
}

// ---------------- sequential RNN (merged layers) ----------------
// 64 blocks, each owns 16 output cols of BOTH layers. Phase p computes
// h0[p] AND h1[p-1] (software-pipelined). LDS: Wh0 slice (32KB) + Win1 slice
// (32KB) + Wh1 slice (32KB) = 96KB.
//
// Why merged (round-6 restructure): rounds 2-5 showed the period is dominated
// by SYNC EVENTS (fabric-paced flag polls ~0.8-1.5us each + store drains), and
// the split L0/L1 design paid 3 rendezvous per logical step (L0:f0, L1:f0+f1).
// Merged: ONE rendezvous per phase, one drain, one flag bump, and the h0[p-1]
// tile load is SHARED by both halves (h0[p]=f(h0[p-1]); h1[p-1]=f(h0[p-1],
// h1[p-2])) -> 256KB loaded per block-phase instead of 384KB.
// Dependency: phase p needs h0[p-1] (slot p) and h1[p-2] (slot p-1), both
// published exactly when all flags >= p. Buffers write-once -> no WAR.
// Loads are PLAIN cached loads (round-5 showed forced asm load batches
// regress vs the compiler's schedule); stores are sc0sc1 write-through.

__global__ __launch_bounds__(256, 1) void rnn_step_kernel(
    const bf16_t* __restrict__ X0,     // [8192][1024] = x@W_in0^T + b0
    const bf16_t* __restrict__ Wh0b,
    const bf16_t* __restrict__ Win1b,
    const bf16_t* __restrict__ Wh1b,
    const float*  __restrict__ b1,
    bf16_t* __restrict__ h0all,        // [129][64][1024], slot s = h0[s-1]
    bf16_t* __restrict__ h1all,        // [129][64][1024], slot s = h1[s-1]
    int* __restrict__ flags)           // [cb*FSTRIDE], cb = 0..63
{
    __shared__ __align__(16) char smem[98304];
    const int tid  = threadIdx.x;
    const int lane = tid & 63;
    const int wave = tid >> 6;
    const int quad = lane >> 4;
    const int l16  = lane & 15;
    const int cb    = blockIdx.x;          // 0..63
    const int cbase = cb * 16;
    const int colg  = cbase + l16;
    const int arow  = (wave * 16 + l16) * HDIM;
    const int orow0 = wave * 16 + quad * 4;
    const floatx4 fzero = {0.f, 0.f, 0.f, 0.f};

    // ---- stage weight slices into LDS (once): Wh0 | Win1 | Wh1 ----
    {
        #pragma unroll
        for (int s = 0; s < 3; ++s) {
            const bf16_t* Ws = (s == 0) ? Wh0b : (s == 1) ? Win1b : Wh1b;
            for (int c = tid; c < 2048; c += 256) {
                int kc2 = c >> 6, ln = c & 63;
                const bf16_t* src = Ws + (size_t)(cbase + (ln & 15)) * HDIM + kc2 * 32 + (ln >> 4) * 8;
                *(int4*)(smem + s * 32768 + c * 16) = *(const int4*)src;
            }
        }
    }
    __syncthreads();

    const float bb = b1[colg];

    float xr[4];
    #pragma unroll
    for (int r = 0; r < 4; ++r)
        xr[r] = (float)X0[(size_t)(orow0 + r) * HDIM + colg];   // X0[0]

    int vc = 0;   // per-lane monotone cache of flags[lane] (wave0 only)
    for (int p = 0; p <= T_STEPS; ++p) {
        if (p > 0) {
            if (wave == 0) {
                while (!__all(vc >= p)) {
                    if (vc < p) {
                        vc = __hip_atomic_load(&flags[lane * FSTRIDE], __ATOMIC_RELAXED,
                                               __HIP_MEMORY_SCOPE_AGENT);
                        if (vc < p) __builtin_amdgcn_s_sleep(1);
                    }
                }
            }
            __syncthreads();
        }

        // shared tile: h0[p-1] = slot p (p=0: initial state, from init kernel)
        const bf16_t* A0 = h0all + (size_t)p * BH;
        bf16x8 av0[32];
        #pragma unroll
        for (int kc = 0; kc < 32; ++kc)
            av0[kc] = *(const bf16x8*)(A0 + arow + kc * 32 + quad * 8);

        // ---- h0 half: h0[p] = tanh(X0[p] + h0[p-1] @ Wh0^T) ----
        if (p < T_STEPS) {
            float xn[4];
            if (p + 1 < T_STEPS) {   // next-step X0, issued early
                #pragma unroll
                for (int r = 0; r < 4; ++r)
                    xn[r] = (float)X0[((size_t)(p + 1) * BATCH + orow0 + r) * HDIM + colg];
            }
            floatx4 a0 = fzero, a1 = fzero;
            #pragma unroll
            for (int kc = 0; kc < 32; ++kc) {
                bf16x8 wv = *(const bf16x8*)(smem + kc * 1024 + lane * 16);
                if (kc & 1) a1 = mfma16(av0[kc], wv, a1);
                else        a0 = mfma16(av0[kc], wv, a0);
            }
            bf16_t* dst = h0all + (size_t)(p + 1) * BH;
            #pragma unroll
            for (int r = 0; r < 4; ++r)
                store_bf16_bypass(dst + (size_t)(orow0 + r) * HDIM + colg,
                                  tanhf(xr[r] + a0[r] + a1[r]));
            if (p + 1 < T_STEPS) {
                #pragma unroll
                for (int r = 0; r < 4; ++r) xr[r] = xn[r];
            }
        }

        // ---- h1 half: h1[p-1] = tanh(h0[p-1] @ Win1^T + h1[p-2] @ Wh1^T + b1) ----
        if (p >= 1) {
            const bf16_t* A1 = h1all + (size_t)(p - 1) * BH;   // h1[p-2]
            bf16x8 av1[32];
            #pragma unroll
            for (int kc = 0; kc < 32; ++kc)
                av1[kc] = *(const bf16x8*)(A1 + arow + kc * 32 + quad * 8);
            floatx4 aA = fzero, aB = fzero;
            #pragma unroll
            for (int kc = 0; kc < 32; ++kc) {
                bf16x8 wv1 = *(const bf16x8*)(smem + 32768 + kc * 1024 + lane * 16);
                if (kc & 1) aB = mfma16(av0[kc], wv1, aB);
                else        aA = mfma16(av0[kc], wv1, aA);
            }
            #pragma unroll
            for (int kc = 0; kc < 32; ++kc) {
                bf16x8 wv2 = *(const bf16x8*)(smem + 65536 + kc * 1024 + lane * 16);
                if (kc & 1) aB = mfma16(av1[kc], wv2, aB);
                else        aA = mfma16(av1[kc], wv2, aA);
            }
            bf16_t* dst = h1all + (size_t)p * BH;
            #pragma unroll
            for (int r = 0; r < 4; ++r)
                store_bf16_bypass(dst + (size_t)(orow0 + r) * HDIM + colg,
                                  tanhf(aA[r] + aB[r] + bb));
        }

        if (p == T_STEPS) break;   // kernel end flushes the last stores

        // ---- publish phase p: one drain + one flag bump ----
        asm volatile("s_waitcnt vmcnt(0)" ::: "memory");  // sc0sc1 stores acked
        __syncthreads();
        if (tid == 0)
            __hip_atomic_store(&flags[cb * FSTRIDE], p + 1, __ATOMIC_RELAXED,
                               __HIP_MEMORY_SCOPE_AGENT);
    }
}

__global__ void finalize_kernel(const bf16_t* __restrict__ h0all,
                                const bf16_t* __restrict__ h1all,
                                float* __restrict__ out) {
    int i = blockIdx.x * blockDim.x + threadIdx.x;   // 65536 threads
    const size_t OUT0 = (size_t)MROWS * VOCAB;
    out[OUT0 + i]                = (float)h0all[(size_t)T_STEPS * BATCH * HDIM + i]; // h0[127]
    out[OUT0 + BATCH * HDIM + i] = (float)h1all[(size_t)T_STEPS * BATCH * HDIM + i]; // h1[127]
}

// ---------------- launcher ----------------

extern "C" void kernel_launch(void* const* d_in, const int* in_sizes, int n_in,
                              void* d_out, int out_size, void* d_ws, size_t ws_size,
                              hipStream_t stream) {
    (void)in_sizes; (void)n_in; (void)out_size; (void)ws_size;
    const float* emb    = (const float*)d_in[0];
    const float* W_in0  = (const float*)d_in[1];
    const float* Wh0    = (const float*)d_in[2];
    const float* b0     = (const float*)d_in[3];
    const float* W_in1  = (const float*)d_in[4];
    const float* Wh1    = (const float*)d_in[5];
    const float* b1     = (const float*)d_in[6];
    const float* Wdec   = (const float*)d_in[7];
    const float* bdec   = (const float*)d_in[8];
    const float* hidden = (const float*)d_in[9];
    const int*   tokens = (const int*)d_in[10];
    float* out = (float*)d_out;

    char* ws = (char*)d_ws;
    auto alloc = [&](size_t bytes) {
        char* p = ws; ws += (bytes + 255) & ~(size_t)255; return p;
    };
    bf16_t* Xemb  = (bf16_t*)alloc((size_t)MROWS * EDIM * 2);
    bf16_t* X0    = (bf16_t*)alloc((size_t)MROWS * HDIM * 2);
    bf16_t* Win0b = (bf16_t*)alloc((size_t)HDIM * EDIM * 2);
    bf16_t* Wh0b  = (bf16_t*)alloc((size_t)HDIM * HDIM * 2);
    bf16_t* Win1b = (bf16_t*)alloc((size_t)HDIM * HDIM * 2);
    bf16_t* Wh1b  = (bf16_t*)alloc((size_t)HDIM * HDIM * 2);
    bf16_t* Wdecb = (bf16_t*)alloc((size_t)VOCAB * HDIM * 2);
    bf16_t* h1all = (bf16_t*)alloc((size_t)(T_STEPS + 1) * BATCH * HDIM * 2);
    bf16_t* h0all = (bf16_t*)alloc((size_t)(T_STEPS + 1) * BATCH * HDIM * 2);
    int*    flags = (int*)alloc(128 * FSTRIDE * 4);

    f2b_kernel<<<dim3(HDIM * EDIM / 1024), 256, 0, stream>>>(W_in0, Win0b, HDIM * EDIM);
    f2b_kernel<<<dim3(HDIM * HDIM / 1024), 256, 0, stream>>>(Wh0,   Wh0b,  HDIM * HDIM);
    f2b_kernel<<<dim3(HDIM * HDIM / 1024), 256, 0, stream>>>(W_in1, Win1b, HDIM * HDIM);
    f2b_kernel<<<dim3(HDIM * HDIM / 1024), 256, 0, stream>>>(Wh1,   Wh1b,  HDIM * HDIM);
    f2b_kernel<<<dim3(VOCAB * HDIM / 1024), 256, 0, stream>>>(Wdec, Wdecb, VOCAB * HDIM);
    gather_kernel<<<dim3(MROWS), 256, 0, stream>>>(emb, tokens, Xemb);
    init_state_kernel<<<dim3(256), 256, 0, stream>>>(hidden, h0all, h1all, flags);

    // X0 = Xemb @ W_in0^T + b0  (bf16 out)
    gemm_kernel<1><<<dim3(HDIM / 128, MROWS / 128), 256, 0, stream>>>(
        Xemb, Win0b, b0, X0, MROWS, HDIM, EDIM);

    rnn_step_kernel<<<dim3(RNN_BLOCKS), 256, 0, stream>>>(
        X0, Wh0b, Win1b, Wh1b, b1, h0all, h1all, flags);

    // logits = h1_all @ Wdec^T + bdec  (fp32 out, straight into d_out)
    gemm_kernel<0><<<dim3((VOCAB + 127) / 128, MROWS / 128), 256, 0, stream>>>(
        h1all + BATCH * HDIM, Wdecb, bdec, out, MROWS, VOCAB, HDIM);

    finalize_kernel<<<dim3(256), 256, 0, stream>>>(h0all, h1all, out);
}

// Round 7
// 1488.665 us; speedup vs baseline: 1.3650x; 1.3650x over previous
//
#include <hip/hip_runtime.h>
#include <hip/hip_bf16.h>
#include <stdint.h>

typedef __bf16 bf16_t;
typedef __bf16 bf16x8 __attribute__((ext_vector_type(8)));
typedef __bf16 bf16x4 __attribute__((ext_vector_type(4)));
typedef float  floatx4 __attribute__((ext_vector_type(4)));

#define T_STEPS 128
#define BATCH   64
#define EDIM    1024
#define HDIM    1024
#define VOCAB   10000
#define MROWS   (T_STEPS * BATCH)   // 8192
#define RNN_BLOCKS 128              // 64 layer-0 + 64 layer-1
#define DEC_BLOCKS 128              // fused decode-GEMM consumer blocks
#define BH      (BATCH * HDIM)
#define FSTRIDE 16                  // flags padded to one 64B line each
#define VTILES  79                  // ceil(10000/128)
#define NUNITS  (64 * VTILES)       // 64 t-pairs x 79 vocab tiles

__device__ __forceinline__ floatx4 mfma16(bf16x8 a, bf16x8 b, floatx4 c) {
    return __builtin_amdgcn_mfma_f32_16x16x32_bf16(a, b, c, 0, 0, 0);
}

// async global->LDS, 16B per lane. LDS dest must be wave-uniform base + lane*16.
__device__ __forceinline__ void gl_lds16(const bf16_t* g, bf16_t* l) {
    __builtin_amdgcn_global_load_lds(
        (const __attribute__((address_space(1))) void*)g,
        (__attribute__((address_space(3))) void*)l, 16, 0, 0);
}

// Coherence-point store: bypasses L1/L2 (sc0 sc1), lands at L3 so other XCDs'
// first-touch plain loads see it WITHOUT any buffer_wbl2/buffer_inv.
__device__ __forceinline__ void store_bf16_bypass(bf16_t* p, float v) {
    union { bf16_t b; unsigned short u; } cv;
    cv.b = (bf16_t)v;
    unsigned int d = cv.u;
    asm volatile("global_store_short %0, %1, off sc0 sc1"
                 :: "v"(p), "v"(d) : "memory");
}

// ---------------- setup kernels ----------------

__global__ void f2b_kernel(const float* __restrict__ s, bf16_t* __restrict__ d, int n) {
    int i = (blockIdx.x * blockDim.x + threadIdx.x) * 4;
    if (i < n) {
        float4 v = *(const float4*)(s + i);
        bf16x4 o;
        o.x = (bf16_t)v.x; o.y = (bf16_t)v.y; o.z = (bf16_t)v.z; o.w = (bf16_t)v.w;
        *(bf16x4*)(d + i) = o;
    }
}

__global__ void gather_kernel(const float* __restrict__ emb, const int* __restrict__ tok,
                              bf16_t* __restrict__ X) {
    int row = blockIdx.x;
    int t = tok[row];
    int e = threadIdx.x * 4;
    float4 v = *(const float4*)(emb + (size_t)t * EDIM + e);
    bf16x4 o;
    o.x = (bf16_t)v.x; o.y = (bf16_t)v.y; o.z = (bf16_t)v.z; o.w = (bf16_t)v.w;
    *(bf16x4*)(X + (size_t)row * EDIM + e) = o;
}

__global__ void init_state_kernel(const float* __restrict__ hidden,
                                  bf16_t* __restrict__ h0all, bf16_t* __restrict__ h1all,
                                  int* __restrict__ flags) {
    int i = blockIdx.x * blockDim.x + threadIdx.x;   // 65536 threads
    h0all[i] = (bf16_t)hidden[i];                    // h0[-1] -> h0all slot 0
    h1all[i] = (bf16_t)hidden[BATCH * HDIM + i];     // h1[-1] -> h1all slot 0
    if (i < 128 * FSTRIDE) flags[i] = 0;             // f0[64] + f1[64], 64B-padded
}

// ---------------- big GEMM: C[M,N] = A[M,K] @ W[N,K]^T + bias ----------------
// 128x128 tile, BK=32, 4 waves (2x2), 4x4 MFMA 16x16x32 per wave (m97 pattern).

template <int OUT_BF16>
__global__ __launch_bounds__(256) void gemm_kernel(
    const bf16_t* __restrict__ A, const bf16_t* __restrict__ W,
    const float* __restrict__ bias, void* __restrict__ out,
    int M, int N, int K)
{
    const int tid  = threadIdx.x;
    const int lane = tid & 63;
    const int wave = tid >> 6;
    const int wm   = wave & 1;
    const int wn   = wave >> 1;
    const int quad = lane >> 4;
    const int l16  = lane & 15;
    const int mTile = blockIdx.y * 128;
    const int nTile = blockIdx.x * 128;

    __shared__ __align__(16) bf16_t sA[128 * 32];
    __shared__ __align__(16) bf16_t sW[128 * 32];

    const floatx4 fzero = {0.f, 0.f, 0.f, 0.f};
    floatx4 acc[4][4];
    #pragma unroll
    for (int i = 0; i < 4; ++i)
        #pragma unroll
        for (int j = 0; j < 4; ++j) acc[i][j] = fzero;

    for (int kk = 0; kk < K; kk += 32) {
        __syncthreads();
        #pragma unroll
        for (int j = 0; j < 2; ++j) {
            int c   = tid + j * 256;
            int row = c >> 2;
            int sub = c & 3;
            gl_lds16(A + (size_t)(mTile + row) * K + kk + sub * 8, sA + c * 8);
            int wrow = nTile + row;
            if (wrow >= N) wrow = N - 1;
            gl_lds16(W + (size_t)wrow * K + kk + sub * 8, sW + c * 8);
        }
        __syncthreads();
        bf16x8 af[4], wf[4];
        #pragma unroll
        for (int mi = 0; mi < 4; ++mi)
            af[mi] = *(const bf16x8*)(sA + (wm * 64 + mi * 16 + l16) * 32 + quad * 8);
        #pragma unroll
        for (int ni = 0; ni < 4; ++ni)
            wf[ni] = *(const bf16x8*)(sW + (wn * 64 + ni * 16 + l16) * 32 + quad * 8);
        #pragma unroll
        for (int mi = 0; mi < 4; ++mi)
            #pragma unroll
            for (int ni = 0; ni < 4; ++ni)
                acc[mi][ni] = mfma16(af[mi], wf[ni], acc[mi][ni]);
    }

    #pragma unroll
    for (int ni = 0; ni < 4; ++ni) {
        int col = nTile + wn * 64 + ni * 16 + l16;
        if (col < N) {
            float bv = bias[col];
            #pragma unroll
            for (int mi = 0; mi < 4; ++mi) {
                #pragma unroll
                for (int r = 0; r < 4; ++r) {
                    int row = mTile + wm * 64 + mi * 16 + quad * 4 + r;
                    float v = acc[mi][ni][r] + bv;
                    if (OUT_BF16) ((bf16_t*)out)[(size_t)row * N + col] = (bf16_t)v;
                    else          ((float*)out)[(size_t)row * N + col] = v;
                }
            }
        }
    }
}

// ---------------- fused RNN + streaming decode ----------------
// 256 blocks, all co-resident (256 CUs), RNN blocks dispatched first:
//   0..63   layer-0 (Wh0 slice in LDS)         -- round-4 structure, verbatim
//   64..127 layer-1 (Win1+Wh1 slices in LDS)
//   128..255 DECODE: consume f1 flags, compute logits[t] = h1[t] @ Wdec^T + bdec
//            as (t-pair x vocab-tile) units with the m97 128x128 GEMM tile.
// Decode units in t-major order: unit u -> tp=u/79, vt=u%79; ready when
// f1[*] >= 2*tp+2 (h1 slots 2tp+1, 2tp+2 written). A-rows = h1all + BH +
// mTile*1024 are CONTIGUOUS across slots. Decode is a pure consumer: nothing
// waits on it -> no deadlock even if a decode block is dispatched late.
// Capacity: decode needs ~4.6 units/us, 128 blocks supply ~12 -> tracks the
// RNN and finishes ~15us after the last flag, removing the serial decode GEMM.

__global__ __launch_bounds__(256, 1) void rnn_step_kernel(
    const bf16_t* __restrict__ X0,     // [8192][1024] = x@W_in0^T + b0
    const bf16_t* __restrict__ Wh0b,
    const bf16_t* __restrict__ Win1b,
    const bf16_t* __restrict__ Wh1b,
    const float*  __restrict__ b1,
    const bf16_t* __restrict__ Wdecb,  // [10000][1024]
    const float*  __restrict__ bdec,   // [10000]
    float* __restrict__ logits,        // [8192][10000] fp32 (d_out)
    bf16_t* __restrict__ h0all,        // [129][64][1024], slot s = h0[s-1]
    bf16_t* __restrict__ h1all,        // [129][64][1024], slot s = h1[s-1]
    int* __restrict__ flags)           // [0..63]*FSTRIDE = f0, +64*FSTRIDE = f1
{
    __shared__ __align__(16) char smem[65536];
    const int tid  = threadIdx.x;
    const int lane = tid & 63;
    const int wave = tid >> 6;
    const int quad = lane >> 4;
    const int l16  = lane & 15;
    int* f0 = flags;
    int* f1 = flags + 64 * FSTRIDE;
    const floatx4 fzero = {0.f, 0.f, 0.f, 0.f};

    if (blockIdx.x >= RNN_BLOCKS) {
        // ================= decode blocks =================
        const int d  = blockIdx.x - RNN_BLOCKS;
        const int wm = wave & 1;
        const int wn = wave >> 1;
        bf16_t* sA = (bf16_t*)smem;            // 8 KB
        bf16_t* sW = (bf16_t*)(smem + 8192);   // 8 KB
        const bf16_t* Adec = h1all + BH;       // row r = h1[r/64][r%64]
        int vc = 0;
        for (int u = d; u < NUNITS; u += DEC_BLOCKS) {
            const int tp = u / VTILES;
            const int vt = u - tp * VTILES;
            const int need = 2 * tp + 2;
            if (wave == 0) {
                while (!__all(vc >= need)) {
                    if (vc < need) {
                        vc = __hip_atomic_load(&f1[lane * FSTRIDE], __ATOMIC_RELAXED,
                                               __HIP_MEMORY_SCOPE_AGENT);
                        if (vc < need) __builtin_amdgcn_s_sleep(32);
                    }
                }
            }
            __syncthreads();
            const int mTile = tp * 128;
            const int nTile = vt * 128;
            floatx4 acc[4][4];
            #pragma unroll
            for (int i = 0; i < 4; ++i)
                #pragma unroll
                for (int j = 0; j < 4; ++j) acc[i][j] = fzero;
            for (int kk = 0; kk < HDIM; kk += 32) {
                __syncthreads();
                #pragma unroll
                for (int j = 0; j < 2; ++j) {
                    int c   = tid + j * 256;
                    int row = c >> 2;
                    int sub = c & 3;
                    gl_lds16(Adec + (size_t)(mTile + row) * HDIM + kk + sub * 8, sA + c * 8);
                    int wrow = nTile + row;
                    if (wrow >= VOCAB) wrow = VOCAB - 1;
                    gl_lds16(Wdecb + (size_t)wrow * HDIM + kk + sub * 8, sW + c * 8);
                }
                __syncthreads();
                bf16x8 af[4], wf[4];
                #pragma unroll
                for (int mi = 0; mi < 4; ++mi)
                    af[mi] = *(const bf16x8*)(sA + (wm * 64 + mi * 16 + l16) * 32 + quad * 8);
                #pragma unroll
                for (int ni = 0; ni < 4; ++ni)
                    wf[ni] = *(const bf16x8*)(sW + (wn * 64 + ni * 16 + l16) * 32 + quad * 8);
                #pragma unroll
                for (int mi = 0; mi < 4; ++mi)
                    #pragma unroll
                    for (int ni = 0; ni < 4; ++ni)
                        acc[mi][ni] = mfma16(af[mi], wf[ni], acc[mi][ni]);
            }
            #pragma unroll
            for (int ni = 0; ni < 4; ++ni) {
                int col = nTile + wn * 64 + ni * 16 + l16;
                if (col < VOCAB) {
                    float bv = bdec[col];
                    #pragma unroll
                    for (int mi = 0; mi < 4; ++mi) {
                        #pragma unroll
                        for (int r = 0; r < 4; ++r) {
                            int row = mTile + wm * 64 + mi * 16 + quad * 4 + r;
                            logits[(size_t)row * VOCAB + col] = acc[mi][ni][r] + bv;
                        }
                    }
                }
            }
            __syncthreads();   // LDS reuse guard before next unit's staging
        }
        return;
    }

    // ================= RNN blocks (round-4 structure, verbatim) =================
    const bool isL1 = blockIdx.x >= 64;
    const int cb    = blockIdx.x & 63;
    const int cbase = cb * 16;
    const int colg  = cbase + l16;
    const int arow  = (wave * 16 + l16) * HDIM;
    const int orow0 = wave * 16 + quad * 4;

    // ---- stage weight slices into LDS (once) ----
    {
        const bf16_t* W0 = isL1 ? Win1b : Wh0b;
        for (int c = tid; c < 2048; c += 256) {
            int kc2 = c >> 6, ln = c & 63;
            const bf16_t* src = W0 + (size_t)(cbase + (ln & 15)) * HDIM + kc2 * 32 + (ln >> 4) * 8;
            *(int4*)(smem + c * 16) = *(const int4*)src;
        }
        if (isL1) {
            for (int c = tid; c < 2048; c += 256) {
                int kc2 = c >> 6, ln = c & 63;
                const bf16_t* src = Wh1b + (size_t)(cbase + (ln & 15)) * HDIM + kc2 * 32 + (ln >> 4) * 8;
                *(int4*)(smem + 32768 + c * 16) = *(const int4*)src;
            }
        }
    }
    __syncthreads();

    if (!isL1) {
        // ---------------- layer 0 ----------------
        float xr[4];
        #pragma unroll
        for (int r = 0; r < 4; ++r)
            xr[r] = (float)X0[(size_t)(orow0 + r) * HDIM + colg];
        int vc = 0;   // per-lane monotone cache of f0[lane] (wave0 only)
        for (int t = 0; t < T_STEPS; ++t) {
            if (t > 0) {
                if (wave == 0) {
                    while (!__all(vc >= t)) {
                        if (vc < t) {
                            vc = __hip_atomic_load(&f0[lane * FSTRIDE], __ATOMIC_RELAXED,
                                                   __HIP_MEMORY_SCOPE_AGENT);
                            if (vc < t) __builtin_amdgcn_s_sleep(1);
                        }
                    }
                }
                __syncthreads();
            }
            const bf16_t* Ap = h0all + (size_t)t * BH;
            bf16x8 av[32];
            #pragma unroll
            for (int kc = 0; kc < 32; ++kc)
                av[kc] = *(const bf16x8*)(Ap + arow + kc * 32 + quad * 8);
            float xn[4];
            if (t + 1 < T_STEPS) {
                #pragma unroll
                for (int r = 0; r < 4; ++r)
                    xn[r] = (float)X0[((size_t)(t + 1) * BATCH + orow0 + r) * HDIM + colg];
            }
            __builtin_amdgcn_sched_barrier(0);
            floatx4 a0 = fzero, a1 = fzero;
            #pragma unroll
            for (int kc = 0; kc < 32; ++kc) {
                bf16x8 wv = *(const bf16x8*)(smem + kc * 1024 + lane * 16);
                if (kc & 1) a1 = mfma16(av[kc], wv, a1);
                else        a0 = mfma16(av[kc], wv, a0);
            }
            bf16_t* dst = h0all + (size_t)(t + 1) * BH;
            #pragma unroll
            for (int r = 0; r < 4; ++r)
                store_bf16_bypass(dst + (size_t)(orow0 + r) * HDIM + colg,
                                  tanhf(xr[r] + a0[r] + a1[r]));
            if (t + 1 < T_STEPS) {
                #pragma unroll
                for (int r = 0; r < 4; ++r) xr[r] = xn[r];
            }
            asm volatile("s_waitcnt vmcnt(0)" ::: "memory");
            __syncthreads();
            if (tid == 0)
                __hip_atomic_store(&f0[cb * FSTRIDE], t + 1, __ATOMIC_RELAXED,
                                   __HIP_MEMORY_SCOPE_AGENT);
        }
    } else {
        // ---------------- layer 1 ----------------
        const float bb = b1[colg];
        int vc0 = 0, vc1 = 0;
        for (int t = 0; t < T_STEPS; ++t) {
            if (wave == 0) {
                while (!__all(vc0 >= t + 1)) {
                    if (vc0 < t + 1) {
                        vc0 = __hip_atomic_load(&f0[lane * FSTRIDE], __ATOMIC_RELAXED,
                                                __HIP_MEMORY_SCOPE_AGENT);
                        if (vc0 < t + 1) __builtin_amdgcn_s_sleep(1);
                    }
                }
            }
            __syncthreads();
            const bf16_t* A0 = h0all + (size_t)(t + 1) * BH;
            bf16x8 av0[32];
            #pragma unroll
            for (int kc = 0; kc < 32; ++kc)
                av0[kc] = *(const bf16x8*)(A0 + arow + kc * 32 + quad * 8);
            __builtin_amdgcn_sched_barrier(0);
            floatx4 aA = fzero, aB = fzero;
            #pragma unroll
            for (int kc = 0; kc < 32; ++kc) {
                bf16x8 wv1 = *(const bf16x8*)(smem + kc * 1024 + lane * 16);
                if (kc & 1) aB = mfma16(av0[kc], wv1, aB);
                else        aA = mfma16(av0[kc], wv1, aA);
            }
            if (t > 0) {
                if (wave == 0) {
                    while (!__all(vc1 >= t)) {
                        if (vc1 < t) {
                            vc1 = __hip_atomic_load(&f1[lane * FSTRIDE], __ATOMIC_RELAXED,
                                                    __HIP_MEMORY_SCOPE_AGENT);
                            if (vc1 < t) __builtin_amdgcn_s_sleep(1);
                        }
                    }
                }
                __syncthreads();
            }
            const bf16_t* A1 = h1all + (size_t)t * BH;
            bf16x8 av1[32];
            #pragma unroll
            for (int kc = 0; kc < 32; ++kc)
                av1[kc] = *(const bf16x8*)(A1 + arow + kc * 32 + quad * 8);
            __builtin_amdgcn_sched_barrier(0);
            #pragma unroll
            for (int kc = 0; kc < 32; ++kc) {
                bf16x8 wv2 = *(const bf16x8*)(smem + 32768 + kc * 1024 + lane * 16);
                if (kc & 1) aB = mfma16(av1[kc], wv2, aB);
                else        aA = mfma16(av1[kc], wv2, aA);
            }
            bf16_t* dst = h1all + (size_t)(t + 1) * BH;
            #pragma unroll
            for (int r = 0; r < 4; ++r)
                store_bf16_bypass(dst + (size_t)(orow0 + r) * HDIM + colg,
                                  tanhf(aA[r] + aB[r] + bb));
            asm volatile("s_waitcnt vmcnt(0)" ::: "memory");
            __syncthreads();
            if (tid == 0)
                __hip_atomic_store(&f1[cb * FSTRIDE], t + 1, __ATOMIC_RELAXED,
                                   __HIP_MEMORY_SCOPE_AGENT);
        }
    }
}

__global__ void finalize_kernel(const bf16_t* __restrict__ h0all,
                                const bf16_t* __restrict__ h1all,
                                float* __restrict__ out) {
    int i = blockIdx.x * blockDim.x + threadIdx.x;   // 65536 threads
    const size_t OUT0 = (size_t)MROWS * VOCAB;
    out[OUT0 + i]                = (float)h0all[(size_t)T_STEPS * BATCH * HDIM + i]; // h0[127]
    out[OUT0 + BATCH * HDIM + i] = (float)h1all[(size_t)T_STEPS * BATCH * HDIM + i]; // h1[127]
}

// ---------------- launcher ----------------

extern "C" void kernel_launch(void* const* d_in, const int* in_sizes, int n_in,
                              void* d_out, int out_size, void* d_ws, size_t ws_size,
                              hipStream_t stream) {
    (void)in_sizes; (void)n_in; (void)out_size; (void)ws_size;
    const float* emb    = (const float*)d_in[0];
    const float* W_in0  = (const float*)d_in[1];
    const float* Wh0    = (const float*)d_in[2];
    const float* b0     = (const float*)d_in[3];
    const float* W_in1  = (const float*)d_in[4];
    const float* Wh1    = (const float*)d_in[5];
    const float* b1     = (const float*)d_in[6];
    const float* Wdec   = (const float*)d_in[7];
    const float* bdec   = (const float*)d_in[8];
    const float* hidden = (const float*)d_in[9];
    const int*   tokens = (const int*)d_in[10];
    float* out = (float*)d_out;

    char* ws = (char*)d_ws;
    auto alloc = [&](size_t bytes) {
        char* p = ws; ws += (bytes + 255) & ~(size_t)255; return p;
    };
    bf16_t* Xemb  = (bf16_t*)alloc((size_t)MROWS * EDIM * 2);
    bf16_t* X0    = (bf16_t*)alloc((size_t)MROWS * HDIM * 2);
    bf16_t* Win0b = (bf16_t*)alloc((size_t)HDIM * EDIM * 2);
    bf16_t* Wh0b  = (bf16_t*)alloc((size_t)HDIM * HDIM * 2);
    bf16_t* Win1b = (bf16_t*)alloc((size_t)HDIM * HDIM * 2);
    bf16_t* Wh1b  = (bf16_t*)alloc((size_t)HDIM * HDIM * 2);
    bf16_t* Wdecb = (bf16_t*)alloc((size_t)VOCAB * HDIM * 2);
    bf16_t* h1all = (bf16_t*)alloc((size_t)(T_STEPS + 1) * BATCH * HDIM * 2);
    bf16_t* h0all = (bf16_t*)alloc((size_t)(T_STEPS + 1) * BATCH * HDIM * 2);
    int*    flags = (int*)alloc(128 * FSTRIDE * 4);

    f2b_kernel<<<dim3(HDIM * EDIM / 1024), 256, 0, stream>>>(W_in0, Win0b, HDIM * EDIM);
    f2b_kernel<<<dim3(HDIM * HDIM / 1024), 256, 0, stream>>>(Wh0,   Wh0b,  HDIM * HDIM);
    f2b_kernel<<<dim3(HDIM * HDIM / 1024), 256, 0, stream>>>(W_in1, Win1b, HDIM * HDIM);
    f2b_kernel<<<dim3(HDIM * HDIM / 1024), 256, 0, stream>>>(Wh1,   Wh1b,  HDIM * HDIM);
    f2b_kernel<<<dim3(VOCAB * HDIM / 1024), 256, 0, stream>>>(Wdec, Wdecb, VOCAB * HDIM);
    gather_kernel<<<dim3(MROWS), 256, 0, stream>>>(emb, tokens, Xemb);
    init_state_kernel<<<dim3(256), 256, 0, stream>>>(hidden, h0all, h1all, flags);

    // X0 = Xemb @ W_in0^T + b0  (bf16 out)
    gemm_kernel<1><<<dim3(HDIM / 128, MROWS / 128), 256, 0, stream>>>(
        Xemb, Win0b, b0, X0, MROWS, HDIM, EDIM);

    // fused RNN + streaming decode (decode GEMM folded onto the idle 128 CUs)
    rnn_step_kernel<<<dim3(RNN_BLOCKS + DEC_BLOCKS), 256, 0, stream>>>(
        X0, Wh0b, Win1b, Wh1b, b1, Wdecb, bdec, out, h0all, h1all, flags);

    finalize_kernel<<<dim3(256), 256, 0, stream>>>(h0all, h1all, out);
}